// Round 4
// baseline (442.274 us; speedup 1.0000x reference)
//
#include <hip/hip_runtime.h>
#include <math.h>

// GaussianLayer: per row (B=524288): mu=x[0], sigma=exp(0.5*x[1]);
// pdf over xx=-99..99, cumsum over 199 bins. Output (B,199) fp32 = 417 MB.
//
// Accounting: dur_us includes the harness ~265 us / 1.67 GB poison fill.
// Kernel-proper ~150 us vs 67 us at the fill's demonstrated 6.26 TB/s.
//
// Falsified: write-allocate fetch (R6), L2-bypass (R7: poison clobber ->
// NaN), inter-block stalls (R8 persistent: null), barrier/LDS structure
// (R9 wave-autonomous scan: null). Three disjoint structures = same
// ~150 us -> the limiter is shared. The one shared trait: each wave/block
// streams a PRIVATE contiguous 25-50 KB run, so the instantaneous write
// front is 1.5K-8K scattered streams -> randomized HBM page access.
// The fill runs ~800 lockstep waves grid-strided: dense ~1 MB contiguous
// front, near-sequential per channel -> 6.26 TB/s.
//
// R10 = R9 body, task order flipped to fill-style: wave w handles rows
// w, w+W, w+2W... (W=3072, 12 waves/CU). Concurrent rows are adjacent ->
// dense ~2.4 MB moving write front. Params gathered per 64-row group
// (lane l pre-loads row w+(k0+l)W; broadcast via readlane at sub-iter l).

#define NT   256
#define GRID 768                  // 3 blocks/CU
#define WTOT (GRID * (NT / 64))   // 3072 waves, 12/CU

typedef float fx4 __attribute__((ext_vector_type(4)));

__device__ __forceinline__ float bcast(float v, int lane) {
    return __int_as_float(__builtin_amdgcn_readlane(__float_as_int(v), lane));
}

__global__ __launch_bounds__(NT, 3)
void gauss_cdf_kernel(const float2* __restrict__ x, float* __restrict__ out, int B) {
    const int l = threadIdx.x & 63;
    const int w = blockIdx.x * (NT / 64) + (threadIdx.x >> 6);  // 0..WTOT-1

    const float bl   = 4.0f * (float)l - 99.0f;  // first bin center offset
    const bool  full = (l <= 48);                // 4 valid bins
    const bool  any  = (l <= 49);                // lane 49: 3 valid bins

    // rows handled by this wave: w, w+WTOT, w+2*WTOT, ... (interleaved order)
    for (int k0 = 0; ; k0 += 64) {
        const long long first = (long long)w + (long long)k0 * WTOT;
        if (first >= B) break;
        const long long rem = (long long)B - first;
        const int imax = (int)((rem + WTOT - 1) / WTOT) < 64
                       ? (int)((rem + WTOT - 1) / WTOT) : 64;

        // lane l pre-gathers params for sub-iteration l of this group
        long long rl = (long long)w + (long long)(k0 + l) * WTOT;
        float2 vx = x[rl < B ? (int)rl : 0];

        #pragma unroll 2
        for (int i = 0; i < imax; ++i) {
            const int row = w + (k0 + i) * WTOT;

            const float mu   = bcast(vx.x, i);
            const float lsig = bcast(vx.y, i);
            // -log2e/2 = -0.72134752; log2(1/sqrt(2pi)) = -1.32574806
            const float li = -1.3257480647361593f - 0.7213475204444817f * lsig;
            const float s  = __builtin_amdgcn_exp2f(-0.7213475204444817f * lsig);
            const float ca = -0.7213475204444817f * s * s;  // -log2e/(2 sigma^2)

            const float t0 = bl - mu, t1 = t0 + 1.f, t2 = t0 + 2.f, t3 = t0 + 3.f;
            float p0 = __builtin_amdgcn_exp2f(__builtin_fmaf(ca, t0 * t0, li));
            float p1 = __builtin_amdgcn_exp2f(__builtin_fmaf(ca, t1 * t1, li));
            float p2 = __builtin_amdgcn_exp2f(__builtin_fmaf(ca, t2 * t2, li));
            float p3 = __builtin_amdgcn_exp2f(__builtin_fmaf(ca, t3 * t3, li));
            if (!any)  { p0 = 0.f; p1 = 0.f; p2 = 0.f; }  // lanes 50..63
            if (!full) { p3 = 0.f; }                       // lane 49: no bin 199

            // in-lane serial cumsum of 4 bins
            const float c0 = p0, c1 = c0 + p1, c2 = c1 + p2, c3 = c2 + p3;

            // inclusive wave scan of lane sums (6 shuffle steps)
            float sc = c3;
            #pragma unroll
            for (int d = 1; d < 64; d <<= 1) {
                float t = __shfl_up(sc, d, 64);
                if (l >= d) sc += t;
            }
            const float e = sc - c3;   // exclusive prefix of earlier lanes

            const float o0 = e + c0, o1 = e + c1, o2 = e + c2, o3 = e + c3;
            float* ro = out + (size_t)row * 199;
            if (full) {
                // 4B-aligned 16B store; memcpy correct under any lowering
                float o4[4] = {o0, o1, o2, o3};
                __builtin_memcpy(ro + 4 * l, o4, 16);
            } else if (l == 49) {
                ro[196] = o0; ro[197] = o1; ro[198] = o2;
            }
        }
    }
}

extern "C" void kernel_launch(void* const* d_in, const int* in_sizes, int n_in,
                              void* d_out, int out_size, void* d_ws, size_t ws_size,
                              hipStream_t stream) {
    const float2* x = (const float2*)d_in[0];
    float* out = (float*)d_out;
    const int B = in_sizes[0] / 2;                    // (B,2) fp32
    gauss_cdf_kernel<<<GRID, NT, 0, stream>>>(x, out, B);
}